// Round 11
// baseline (131.416 us; speedup 1.0000x reference)
//
#include <hip/hip_runtime.h>
#include <math.h>

constexpr int NG  = 8192;        // genes
constexpr int NM  = 256;         // sets
constexpr int NB  = 32;          // batch
constexpr int KR  = 256;         // k-span per k_mm block
constexpr int NKB = NG / KR;     // 32

// Diagnostic replication factors (idempotent reps; opaque offset defeats CSE)
constexpr int REP_PREP  = 16;
constexpr int REP_MM    = 16;
constexpr int REP_FINAL = 32;

// ws: pA bf16[NM][NG] (4MB, sign=neg) | pB bf16[3][NB][NG] (1.5MB: ra, ra*cf, cf)
//     | part f32[NKB][3][NM][NB] (3.2MB) | sumN f32[NM]

using bf16x8 = __attribute__((ext_vector_type(8))) short;
using s16x4  = __attribute__((ext_vector_type(4))) short;
using f32x4  = __attribute__((ext_vector_type(4))) float;

__device__ __forceinline__ float sigmoidf(float x) {
  return __builtin_amdgcn_rcpf(1.0f + __builtin_amdgcn_exp2f(x * -1.442695041f));
}
__device__ __forceinline__ float qrtf(float x) {   // x^0.25
  return __builtin_amdgcn_sqrtf(__builtin_amdgcn_sqrtf(x));
}
__device__ __forceinline__ short bfr(float f) {    // fp32 -> bf16 (RNE)
  unsigned x = __float_as_uint(f);
  return (short)((x + 0x7fffu + ((x >> 16) & 1u)) >> 16);
}
// runtime-opaque zero: compiler can't CSE loads/stores across rep iterations
__device__ __forceinline__ size_t opq0() {
  unsigned z;
  asm volatile("s_mov_b32 %0, 0" : "=s"(z));
  return (size_t)z;
}

// blocks 0..NM-1: thr/sumN + write pA[m][:] = +-ind^0.25 bf16 (sign = neg)
// blocks NM..NM+NB-1: cf row in LDS, then write pB planes (ra, ra*cf, cf) bf16
__global__ __launch_bounds__(256) void k_prep(const int* __restrict__ S,
                                              const float* __restrict__ W,
                                              const float* __restrict__ R,
                                              unsigned short* __restrict__ pA,
                                              unsigned short* __restrict__ pB,
                                              float* __restrict__ sumN) {
  const int tid = threadIdx.x;

  if (blockIdx.x < NM) {
    __shared__ float red[4];
    const int m = blockIdx.x;
    #pragma unroll 1
    for (int rep = 0; rep < REP_PREP; ++rep) {
      const size_t z = opq0();
      __syncthreads();                       // guard red[] across reps
      const float4* w4 = reinterpret_cast<const float4*>(W + (size_t)m * NG + z);
      float4 sg[8];
      float s = 0.f;
      #pragma unroll
      for (int q = 0; q < 8; ++q) {
        float4 v = w4[q * 256 + tid];        // coalesced
        sg[q] = make_float4(sigmoidf(v.x), sigmoidf(v.y), sigmoidf(v.z), sigmoidf(v.w));
        s += sg[q].x + sg[q].y + sg[q].z + sg[q].w;
      }
      #pragma unroll
      for (int off = 32; off > 0; off >>= 1) s += __shfl_xor(s, off, 64);
      if ((tid & 63) == 0) red[tid >> 6] = s;
      __syncthreads();
      const float tm = (red[0] + red[1] + red[2] + red[3]) * (0.3f / (float)NG);
      __syncthreads();
      float sn = 0.f;
      s16x4* dst = reinterpret_cast<s16x4*>(pA + (size_t)m * NG + z);
      #pragma unroll
      for (int q = 0; q < 8; ++q) {
        float vv[4] = {sg[q].x, sg[q].y, sg[q].z, sg[q].w};
        s16x4 po;
        #pragma unroll
        for (int j = 0; j < 4; ++j) {
          float v = vv[j];
          v = (v < tm) ? v * 0.01f : v;        // _set_indicators where()
          const bool ng = v < 0.1f;
          po[j] = (short)(bfr(qrtf(v)) | (ng ? (short)0x8000 : (short)0));
          sn += ng ? 1.f : 0.f;
        }
        dst[q * 256 + tid] = po;               // coalesced 8B stores
      }
      #pragma unroll
      for (int off = 32; off > 0; off >>= 1) sn += __shfl_xor(sn, off, 64);
      if ((tid & 63) == 0) red[tid >> 6] = sn;
      __syncthreads();
      if (tid == 0) sumN[m] = red[0] + red[1] + red[2] + red[3];
    }
  } else {
    __shared__ float row[NG];               // 32 KB cf row
    const int b = blockIdx.x - NM;
    #pragma unroll 1
    for (int rep = 0; rep < REP_PREP; ++rep) {
      const size_t z = opq0();
      __syncthreads();                       // guard row[] across reps
      const int4* s4 = reinterpret_cast<const int4*>(S + (size_t)b * NG + z);
      #pragma unroll
      for (int q = 0; q < 8; ++q) {
        const int i = q * 256 + tid;
        const int4 g4 = s4[i];              // coalesced read
        const int k = i * 4;
        row[g4.x] = (float)(NG - k);        // LDS scatter (cheap)
        row[g4.y] = (float)(NG - (k + 1));
        row[g4.z] = (float)(NG - (k + 2));
        row[g4.w] = (float)(NG - (k + 3));
      }
      __syncthreads();
      const float4* r4 = reinterpret_cast<const float4*>(R + (size_t)b * NG + z);
      const float4* c4 = reinterpret_cast<const float4*>(row);
      s16x4* dra = reinterpret_cast<s16x4*>(pB + 0 * (size_t)NB * NG + (size_t)b * NG + z);
      s16x4* drc = reinterpret_cast<s16x4*>(pB + 1 * (size_t)NB * NG + (size_t)b * NG + z);
      s16x4* dcf = reinterpret_cast<s16x4*>(pB + 2 * (size_t)NB * NG + (size_t)b * NG + z);
      #pragma unroll
      for (int q = 0; q < 8; ++q) {
        const float4 r = r4[q * 256 + tid];
        const float4 c = c4[q * 256 + tid];
        const float ra[4] = {qrtf(r.x), qrtf(r.y), qrtf(r.z), qrtf(r.w)};
        const float cc[4] = {c.x, c.y, c.z, c.w};
        s16x4 pra, prc, pcf;
        #pragma unroll
        for (int j = 0; j < 4; ++j) {
          pra[j] = bfr(ra[j]);
          prc[j] = bfr(ra[j] * cc[j]);         // product at fp32, then round
          pcf[j] = bfr(cc[j]);
        }
        dra[q * 256 + tid] = pra;
        drc[q * 256 + tid] = prc;
        dcf[q * 256 + tid] = pcf;
      }
    }
  }
}

// MFMA split-K: grid (NKB, NM/32); 4 waves/block, each owns a 16m x 16b tile.
// Pure load+MFMA: all operands prepacked bf16. No LDS, no barriers.
__global__ __launch_bounds__(256) void k_mm(const unsigned short* __restrict__ pA,
                                            const unsigned short* __restrict__ pB,
                                            float* __restrict__ part) {
  const int tid  = threadIdx.x;
  const int kb   = blockIdx.x;          // k-block
  const int mt   = blockIdx.y;          // m-tile of 32
  const int wv   = tid >> 6;
  const int mw   = wv >> 1, bw = wv & 1;
  const int lane = tid & 63;
  const int lr   = lane & 15, lk = lane >> 4;

  const int m = mt * 32 + mw * 16 + lr;   // A-side row this lane supplies
  const int b = bw * 16 + lr;             // B-side col this lane supplies

  #pragma unroll 1
  for (int rep = 0; rep < REP_MM; ++rep) {
    const size_t z = opq0();
    const unsigned short* Arow = pA + (size_t)m * NG + z;
    const unsigned short* Bra  = pB + 0 * (size_t)NB * NG + (size_t)b * NG + z;
    const unsigned short* Brc  = pB + 1 * (size_t)NB * NG + (size_t)b * NG + z;
    const unsigned short* Bcf  = pB + 2 * (size_t)NB * NG + (size_t)b * NG + z;

    f32x4 accA = {0.f, 0.f, 0.f, 0.f};
    f32x4 accB = {0.f, 0.f, 0.f, 0.f};
    f32x4 accC = {0.f, 0.f, 0.f, 0.f};

    #pragma unroll
    for (int c = 0; c < KR / 32; ++c) {
      const int g = kb * KR + c * 32 + lk * 8;

      const int4 aw = *reinterpret_cast<const int4*>(Arow + g);
      int4 iaw, nfw;
      iaw.x = aw.x & 0x7FFF7FFF;  iaw.y = aw.y & 0x7FFF7FFF;
      iaw.z = aw.z & 0x7FFF7FFF;  iaw.w = aw.w & 0x7FFF7FFF;
      nfw.x = (int)(((unsigned)(aw.x & 0x80008000) >> 15) * 0x3F80u);
      nfw.y = (int)(((unsigned)(aw.y & 0x80008000) >> 15) * 0x3F80u);
      nfw.z = (int)(((unsigned)(aw.z & 0x80008000) >> 15) * 0x3F80u);
      nfw.w = (int)(((unsigned)(aw.w & 0x80008000) >> 15) * 0x3F80u);
      const bf16x8 fia = __builtin_bit_cast(bf16x8, iaw);
      const bf16x8 fnf = __builtin_bit_cast(bf16x8, nfw);

      const bf16x8 fra = *reinterpret_cast<const bf16x8*>(Bra + g);
      const bf16x8 frc = *reinterpret_cast<const bf16x8*>(Brc + g);
      const bf16x8 fcf = *reinterpret_cast<const bf16x8*>(Bcf + g);

      accA = __builtin_amdgcn_mfma_f32_16x16x32_bf16(fia, fra, accA, 0, 0, 0);
      accB = __builtin_amdgcn_mfma_f32_16x16x32_bf16(fia, frc, accB, 0, 0, 0);
      accC = __builtin_amdgcn_mfma_f32_16x16x32_bf16(fnf, fcf, accC, 0, 0, 0);
    }

    const int md = mt * 32 + mw * 16 + 4 * lk;
    const int bd = bw * 16 + lr;
    float* pz = part + z;
    #pragma unroll
    for (int i = 0; i < 4; ++i) {
      pz[((size_t)(kb * 3 + 0) * NM + md + i) * NB + bd] = accA[i];
      pz[((size_t)(kb * 3 + 1) * NM + md + i) * NB + bd] = accB[i];
      pz[((size_t)(kb * 3 + 2) * NM + md + i) * NB + bd] = accC[i];
    }
  }
}

// grid NM: block m; tid = (kg 8 x b 32); coalesced part reads, LDS tree over kg.
__global__ __launch_bounds__(256) void k_final(const float* __restrict__ part,
                                               const float* __restrict__ sumN,
                                               float* __restrict__ out) {
  __shared__ float rA[256], rB[256], rC[256];
  const int tid = threadIdx.x;
  const int m   = blockIdx.x;
  const int b   = tid & 31;
  const int kg  = tid >> 5;             // 0..7, each covers 4 kb

  #pragma unroll 1
  for (int rep = 0; rep < REP_FINAL; ++rep) {
    const size_t z = opq0();
    __syncthreads();                     // guard rA/rB/rC across reps
    float sA = 0.f, sB = 0.f, sC = 0.f;
    #pragma unroll
    for (int t = 0; t < NKB / 8; ++t) {
      const int kb = kg * (NKB / 8) + t;
      const float* p = part + ((size_t)(kb * 3) * NM + m) * NB + b + z;
      sA += p[0];
      sB += p[(size_t)NM * NB];
      sC += p[2 * (size_t)NM * NB];
    }
    rA[tid] = sA; rB[tid] = sB; rC[tid] = sC;
    __syncthreads();
    if (tid < 128) { rA[tid] += rA[tid + 128]; rB[tid] += rB[tid + 128]; rC[tid] += rC[tid + 128]; }
    __syncthreads();
    if (tid < 64)  { rA[tid] += rA[tid + 64];  rB[tid] += rB[tid + 64];  rC[tid] += rC[tid + 64]; }
    __syncthreads();
    if (tid < 32) {
      const float a  = rA[tid] + rA[tid + 32];
      const float bb = rB[tid] + rB[tid + 32];
      const float c  = rC[tid] + rC[tid + 32];
      const float sN = sumN[m];
      out[(size_t)tid * NM + m + z] =
          (bb / (a + 1e-10f) - c / (sN + 1e-10f)) * (1.0f / (float)NG);
    }
  }
}

extern "C" void kernel_launch(void* const* d_in, const int* in_sizes, int n_in,
                              void* d_out, int out_size, void* d_ws, size_t ws_size,
                              hipStream_t stream) {
  const float* R = (const float*)d_in[0];
  const int*   S = (const int*)d_in[1];
  const float* W = (const float*)d_in[2];
  float* out = (float*)d_out;

  char* ws = (char*)d_ws;
  unsigned short* pA = (unsigned short*)ws;                        // 4 MB
  unsigned short* pB = pA + (size_t)NM * NG;                       // 1.5 MB
  float* part = (float*)(ws + (size_t)NM * NG * 2 + (size_t)3 * NB * NG * 2);  // 3.2 MB
  float* sumN = part + (size_t)NKB * 3 * NM * NB;

  k_prep <<<dim3(NM + NB), dim3(256), 0, stream>>>(S, W, R, pA, pB, sumN);
  k_mm   <<<dim3(NKB, NM / 32), dim3(256), 0, stream>>>(pA, pB, part);
  k_final<<<dim3(NM), dim3(256), 0, stream>>>(part, sumN, out);
}

// Round 12
// 22.218 us; speedup vs baseline: 5.9147x; 5.9147x over previous
//
#include <hip/hip_runtime.h>
#include <math.h>

constexpr int NG  = 8192;        // genes
constexpr int NM  = 256;         // sets
constexpr int NB  = 32;         // batch
constexpr int KR  = 128;         // k-span per k_mm block (2 k-halves of 64)
constexpr int NKB = NG / KR;     // 64

// ws: pA bf16[NM][NG] (4MB, sign=neg) | pB bf16[3][NB][NG] (1.5MB: ra, ra*cf, cf)
//     | part f32[NKB][3][NM][NB] (6.3MB) | sumN f32[NM]   — total ~11.8 MB

using bf16x8 = __attribute__((ext_vector_type(8))) short;
using s16x4  = __attribute__((ext_vector_type(4))) short;
using f32x4  = __attribute__((ext_vector_type(4))) float;

__device__ __forceinline__ float sigmoidf(float x) {
  return __builtin_amdgcn_rcpf(1.0f + __builtin_amdgcn_exp2f(x * -1.442695041f));
}
__device__ __forceinline__ float qrtf(float x) {   // x^0.25
  return __builtin_amdgcn_sqrtf(__builtin_amdgcn_sqrtf(x));
}
__device__ __forceinline__ short bfr(float f) {    // fp32 -> bf16 (RNE)
  unsigned x = __float_as_uint(f);
  return (short)((x + 0x7fffu + ((x >> 16) & 1u)) >> 16);
}

// blocks 0..NM-1: thr/sumN + write pA[m][:] = +-ind^0.25 bf16 (sign = neg)
// blocks NM..NM+NB-1: cf row in LDS, then write pB planes (ra, ra*cf, cf) bf16
__global__ __launch_bounds__(256) void k_prep(const int* __restrict__ S,
                                              const float* __restrict__ W,
                                              const float* __restrict__ R,
                                              unsigned short* __restrict__ pA,
                                              unsigned short* __restrict__ pB,
                                              float* __restrict__ sumN) {
  const int tid = threadIdx.x;

  if (blockIdx.x < NM) {
    __shared__ float red[4];
    const int m = blockIdx.x;
    const float4* w4 = reinterpret_cast<const float4*>(W + (size_t)m * NG);
    float4 sg[8];
    float s = 0.f;
    #pragma unroll
    for (int q = 0; q < 8; ++q) {
      float4 v = w4[q * 256 + tid];          // coalesced
      sg[q] = make_float4(sigmoidf(v.x), sigmoidf(v.y), sigmoidf(v.z), sigmoidf(v.w));
      s += sg[q].x + sg[q].y + sg[q].z + sg[q].w;
    }
    #pragma unroll
    for (int off = 32; off > 0; off >>= 1) s += __shfl_xor(s, off, 64);
    if ((tid & 63) == 0) red[tid >> 6] = s;
    __syncthreads();
    const float tm = (red[0] + red[1] + red[2] + red[3]) * (0.3f / (float)NG);
    float sn = 0.f;
    s16x4* dst = reinterpret_cast<s16x4*>(pA + (size_t)m * NG);
    #pragma unroll
    for (int q = 0; q < 8; ++q) {
      float vv[4] = {sg[q].x, sg[q].y, sg[q].z, sg[q].w};
      s16x4 po;
      #pragma unroll
      for (int j = 0; j < 4; ++j) {
        float v = vv[j];
        v = (v < tm) ? v * 0.01f : v;          // _set_indicators where()
        const bool ng = v < 0.1f;
        po[j] = (short)(bfr(qrtf(v)) | (ng ? (short)0x8000 : (short)0));
        sn += ng ? 1.f : 0.f;
      }
      dst[q * 256 + tid] = po;                 // coalesced 8B stores
    }
    #pragma unroll
    for (int off = 32; off > 0; off >>= 1) sn += __shfl_xor(sn, off, 64);
    if ((tid & 63) == 0) red[tid >> 6] = sn;
    __syncthreads();
    if (tid == 0) sumN[m] = red[0] + red[1] + red[2] + red[3];
  } else {
    __shared__ float row[NG];               // 32 KB cf row
    const int b = blockIdx.x - NM;
    const int4* s4 = reinterpret_cast<const int4*>(S + (size_t)b * NG);
    #pragma unroll
    for (int q = 0; q < 8; ++q) {
      const int i = q * 256 + tid;
      const int4 g4 = s4[i];                // coalesced read
      const int k = i * 4;
      row[g4.x] = (float)(NG - k);          // LDS scatter (cheap)
      row[g4.y] = (float)(NG - (k + 1));
      row[g4.z] = (float)(NG - (k + 2));
      row[g4.w] = (float)(NG - (k + 3));
    }
    __syncthreads();
    const float4* r4 = reinterpret_cast<const float4*>(R + (size_t)b * NG);
    const float4* c4 = reinterpret_cast<const float4*>(row);
    s16x4* dra = reinterpret_cast<s16x4*>(pB + 0 * (size_t)NB * NG + (size_t)b * NG);
    s16x4* drc = reinterpret_cast<s16x4*>(pB + 1 * (size_t)NB * NG + (size_t)b * NG);
    s16x4* dcf = reinterpret_cast<s16x4*>(pB + 2 * (size_t)NB * NG + (size_t)b * NG);
    #pragma unroll
    for (int q = 0; q < 8; ++q) {
      const float4 r = r4[q * 256 + tid];
      const float4 c = c4[q * 256 + tid];
      const float ra[4] = {qrtf(r.x), qrtf(r.y), qrtf(r.z), qrtf(r.w)};
      const float cc[4] = {c.x, c.y, c.z, c.w};
      s16x4 pra, prc, pcf;
      #pragma unroll
      for (int j = 0; j < 4; ++j) {
        pra[j] = bfr(ra[j]);
        prc[j] = bfr(ra[j] * cc[j]);           // product at fp32, then round
        pcf[j] = bfr(cc[j]);
      }
      dra[q * 256 + tid] = pra;
      drc[q * 256 + tid] = prc;
      dcf[q * 256 + tid] = pcf;
    }
  }
}

// MFMA split-K, occupancy-fixed: grid (NKB, NM/16) = (64,16) = 1024 blocks
// (4 blocks/CU -> 4 waves/SIMD). 4 waves = bw(2) x ks(2); each wave owns a
// 16m x 16b x 64k slab (2 chunks x 3 MFMA). k-halves combine via LDS reduce
// (stride-13 pad, conflict-free), so part stays NKB=64 (6.3 MB).
// Layout (m89-verified): lane supplies row/col = lane&15 at k = 8*(lane>>4)+e;
// D: m = 4*(lane>>4)+reg, b = lane&15.
__global__ __launch_bounds__(256) void k_mm(const unsigned short* __restrict__ pA,
                                            const unsigned short* __restrict__ pB,
                                            float* __restrict__ part) {
  __shared__ float lred[2][64][13];     // [bw][lane][12 accs + pad] ~6.8 KB
  const int tid  = threadIdx.x;
  const int kb   = blockIdx.x;          // k-block of 128
  const int mt   = blockIdx.y;          // m-tile of 16
  const int wv   = tid >> 6;
  const int bw   = wv & 1, ks = wv >> 1;
  const int lane = tid & 63;
  const int lr   = lane & 15, lk = lane >> 4;

  const int m = mt * 16 + lr;             // A-side row this lane supplies
  const int b = bw * 16 + lr;             // B-side col this lane supplies

  const unsigned short* Arow = pA + (size_t)m * NG;
  const unsigned short* Bra  = pB + 0 * (size_t)NB * NG + (size_t)b * NG;
  const unsigned short* Brc  = pB + 1 * (size_t)NB * NG + (size_t)b * NG;
  const unsigned short* Bcf  = pB + 2 * (size_t)NB * NG + (size_t)b * NG;

  f32x4 accA = {0.f, 0.f, 0.f, 0.f};
  f32x4 accB = {0.f, 0.f, 0.f, 0.f};
  f32x4 accC = {0.f, 0.f, 0.f, 0.f};

  #pragma unroll
  for (int c = 0; c < 2; ++c) {
    const int g = kb * KR + ks * 64 + c * 32 + lk * 8;

    const int4 aw = *reinterpret_cast<const int4*>(Arow + g);
    int4 iaw, nfw;
    iaw.x = aw.x & 0x7FFF7FFF;  iaw.y = aw.y & 0x7FFF7FFF;
    iaw.z = aw.z & 0x7FFF7FFF;  iaw.w = aw.w & 0x7FFF7FFF;
    // sign bits -> bf16 1.0 per halfword: (t>>15)*0x3F80 (no cross-terms)
    nfw.x = (int)(((unsigned)(aw.x & 0x80008000) >> 15) * 0x3F80u);
    nfw.y = (int)(((unsigned)(aw.y & 0x80008000) >> 15) * 0x3F80u);
    nfw.z = (int)(((unsigned)(aw.z & 0x80008000) >> 15) * 0x3F80u);
    nfw.w = (int)(((unsigned)(aw.w & 0x80008000) >> 15) * 0x3F80u);
    const bf16x8 fia = __builtin_bit_cast(bf16x8, iaw);
    const bf16x8 fnf = __builtin_bit_cast(bf16x8, nfw);

    const bf16x8 fra = *reinterpret_cast<const bf16x8*>(Bra + g);
    const bf16x8 frc = *reinterpret_cast<const bf16x8*>(Brc + g);
    const bf16x8 fcf = *reinterpret_cast<const bf16x8*>(Bcf + g);

    accA = __builtin_amdgcn_mfma_f32_16x16x32_bf16(fia, fra, accA, 0, 0, 0);
    accB = __builtin_amdgcn_mfma_f32_16x16x32_bf16(fia, frc, accB, 0, 0, 0);
    accC = __builtin_amdgcn_mfma_f32_16x16x32_bf16(fnf, fcf, accC, 0, 0, 0);
  }

  // combine the two k-half waves (ks=1 -> LDS, ks=0 adds and stores)
  if (ks == 1) {
    #pragma unroll
    for (int i = 0; i < 4; ++i) {
      lred[bw][lane][i]     = accA[i];
      lred[bw][lane][4 + i] = accB[i];
      lred[bw][lane][8 + i] = accC[i];
    }
  }
  __syncthreads();
  if (ks == 0) {
    #pragma unroll
    for (int i = 0; i < 4; ++i) {
      accA[i] += lred[bw][lane][i];
      accB[i] += lred[bw][lane][4 + i];
      accC[i] += lred[bw][lane][8 + i];
    }
    // store: lane, reg i -> (m = mt*16 + 4*lk + i, b = bw*16 + lr)
    const int md = mt * 16 + 4 * lk;
    const int bd = bw * 16 + lr;
    #pragma unroll
    for (int i = 0; i < 4; ++i) {
      part[((size_t)(kb * 3 + 0) * NM + md + i) * NB + bd] = accA[i];
      part[((size_t)(kb * 3 + 1) * NM + md + i) * NB + bd] = accB[i];
      part[((size_t)(kb * 3 + 2) * NM + md + i) * NB + bd] = accC[i];
    }
  }
}

// grid NM: block m; tid = (kg 8 x b 32); coalesced part reads, LDS tree over kg.
__global__ __launch_bounds__(256) void k_final(const float* __restrict__ part,
                                               const float* __restrict__ sumN,
                                               float* __restrict__ out) {
  __shared__ float rA[256], rB[256], rC[256];
  const int tid = threadIdx.x;
  const int m   = blockIdx.x;
  const int b   = tid & 31;
  const int kg  = tid >> 5;             // 0..7, each covers 8 kb

  float sA = 0.f, sB = 0.f, sC = 0.f;
  #pragma unroll
  for (int t = 0; t < NKB / 8; ++t) {
    const int kb = kg * (NKB / 8) + t;
    const float* p = part + ((size_t)(kb * 3) * NM + m) * NB + b;
    sA += p[0];
    sB += p[(size_t)NM * NB];
    sC += p[2 * (size_t)NM * NB];
  }
  rA[tid] = sA; rB[tid] = sB; rC[tid] = sC;
  __syncthreads();
  if (tid < 128) { rA[tid] += rA[tid + 128]; rB[tid] += rB[tid + 128]; rC[tid] += rC[tid + 128]; }
  __syncthreads();
  if (tid < 64)  { rA[tid] += rA[tid + 64];  rB[tid] += rB[tid + 64];  rC[tid] += rC[tid + 64]; }
  __syncthreads();
  if (tid < 32) {
    const float a  = rA[tid] + rA[tid + 32];
    const float bb = rB[tid] + rB[tid + 32];
    const float c  = rC[tid] + rC[tid + 32];
    const float sN = sumN[m];
    out[(size_t)tid * NM + m] = (bb / (a + 1e-10f) - c / (sN + 1e-10f)) * (1.0f / (float)NG);
  }
}

extern "C" void kernel_launch(void* const* d_in, const int* in_sizes, int n_in,
                              void* d_out, int out_size, void* d_ws, size_t ws_size,
                              hipStream_t stream) {
  const float* R = (const float*)d_in[0];
  const int*   S = (const int*)d_in[1];
  const float* W = (const float*)d_in[2];
  float* out = (float*)d_out;

  char* ws = (char*)d_ws;
  unsigned short* pA = (unsigned short*)ws;                        // 4 MB
  unsigned short* pB = pA + (size_t)NM * NG;                       // 1.5 MB
  float* part = (float*)(ws + (size_t)NM * NG * 2 + (size_t)3 * NB * NG * 2);  // 6.3 MB
  float* sumN = part + (size_t)NKB * 3 * NM * NB;

  k_prep <<<dim3(NM + NB), dim3(256), 0, stream>>>(S, W, R, pA, pB, sumN);
  k_mm   <<<dim3(NKB, NM / 16), dim3(256), 0, stream>>>(pA, pB, part);
  k_final<<<dim3(NM), dim3(256), 0, stream>>>(part, sumN, out);
}

// Round 13
// 20.383 us; speedup vs baseline: 6.4472x; 1.0900x over previous
//
#include <hip/hip_runtime.h>
#include <math.h>

constexpr int NG  = 8192;        // genes
constexpr int NM  = 256;         // sets
constexpr int NB  = 32;          // batch
constexpr int KR  = 256;         // k-span per k_mm block
constexpr int NKB = NG / KR;     // 32

// ws: pA bf16[NM][NG] (4MB, sign=neg) | pB bf16[3][NB][NG] (1.5MB: ra, ra*cf, cf)
//     | part f32[NKB][3][NM][NB] (3.2MB) | sumN f32[NM]

using bf16x8 = __attribute__((ext_vector_type(8))) short;
using s16x4  = __attribute__((ext_vector_type(4))) short;
using f32x4  = __attribute__((ext_vector_type(4))) float;

__device__ __forceinline__ float sigmoidf(float x) {
  return __builtin_amdgcn_rcpf(1.0f + __builtin_amdgcn_exp2f(x * -1.442695041f));
}
__device__ __forceinline__ float qrtf(float x) {   // x^0.25
  return __builtin_amdgcn_sqrtf(__builtin_amdgcn_sqrtf(x));
}
__device__ __forceinline__ short bfr(float f) {    // fp32 -> bf16 (RNE)
  unsigned x = __float_as_uint(f);
  return (short)((x + 0x7fffu + ((x >> 16) & 1u)) >> 16);
}

// blocks 0..NM-1: thr/sumN + write pA[m][:] = +-ind^0.25 bf16 (sign = neg)
// blocks NM..NM+NB-1: cf row in LDS, then write pB planes (ra, ra*cf, cf) bf16
__global__ __launch_bounds__(256) void k_prep(const int* __restrict__ S,
                                              const float* __restrict__ W,
                                              const float* __restrict__ R,
                                              unsigned short* __restrict__ pA,
                                              unsigned short* __restrict__ pB,
                                              float* __restrict__ sumN) {
  const int tid = threadIdx.x;

  if (blockIdx.x < NM) {
    __shared__ float red[4];
    const int m = blockIdx.x;
    const float4* w4 = reinterpret_cast<const float4*>(W + (size_t)m * NG);
    float4 sg[8];
    float s = 0.f;
    #pragma unroll
    for (int q = 0; q < 8; ++q) {
      float4 v = w4[q * 256 + tid];          // coalesced
      sg[q] = make_float4(sigmoidf(v.x), sigmoidf(v.y), sigmoidf(v.z), sigmoidf(v.w));
      s += sg[q].x + sg[q].y + sg[q].z + sg[q].w;
    }
    #pragma unroll
    for (int off = 32; off > 0; off >>= 1) s += __shfl_xor(s, off, 64);
    if ((tid & 63) == 0) red[tid >> 6] = s;
    __syncthreads();
    const float tm = (red[0] + red[1] + red[2] + red[3]) * (0.3f / (float)NG);
    float sn = 0.f;
    s16x4* dst = reinterpret_cast<s16x4*>(pA + (size_t)m * NG);
    #pragma unroll
    for (int q = 0; q < 8; ++q) {
      float vv[4] = {sg[q].x, sg[q].y, sg[q].z, sg[q].w};
      s16x4 po;
      #pragma unroll
      for (int j = 0; j < 4; ++j) {
        float v = vv[j];
        v = (v < tm) ? v * 0.01f : v;          // _set_indicators where()
        const bool ng = v < 0.1f;
        po[j] = (short)(bfr(qrtf(v)) | (ng ? (short)0x8000 : (short)0));
        sn += ng ? 1.f : 0.f;
      }
      dst[q * 256 + tid] = po;                 // coalesced 8B stores
    }
    #pragma unroll
    for (int off = 32; off > 0; off >>= 1) sn += __shfl_xor(sn, off, 64);
    if ((tid & 63) == 0) red[tid >> 6] = sn;
    __syncthreads();
    if (tid == 0) sumN[m] = red[0] + red[1] + red[2] + red[3];
  } else {
    __shared__ float row[NG];               // 32 KB cf row
    const int b = blockIdx.x - NM;
    const int4* s4 = reinterpret_cast<const int4*>(S + (size_t)b * NG);
    #pragma unroll
    for (int q = 0; q < 8; ++q) {
      const int i = q * 256 + tid;
      const int4 g4 = s4[i];                // coalesced read
      const int k = i * 4;
      row[g4.x] = (float)(NG - k);          // LDS scatter (cheap)
      row[g4.y] = (float)(NG - (k + 1));
      row[g4.z] = (float)(NG - (k + 2));
      row[g4.w] = (float)(NG - (k + 3));
    }
    __syncthreads();
    const float4* r4 = reinterpret_cast<const float4*>(R + (size_t)b * NG);
    const float4* c4 = reinterpret_cast<const float4*>(row);
    s16x4* dra = reinterpret_cast<s16x4*>(pB + 0 * (size_t)NB * NG + (size_t)b * NG);
    s16x4* drc = reinterpret_cast<s16x4*>(pB + 1 * (size_t)NB * NG + (size_t)b * NG);
    s16x4* dcf = reinterpret_cast<s16x4*>(pB + 2 * (size_t)NB * NG + (size_t)b * NG);
    #pragma unroll
    for (int q = 0; q < 8; ++q) {
      const float4 r = r4[q * 256 + tid];
      const float4 c = c4[q * 256 + tid];
      const float ra[4] = {qrtf(r.x), qrtf(r.y), qrtf(r.z), qrtf(r.w)};
      const float cc[4] = {c.x, c.y, c.z, c.w};
      s16x4 pra, prc, pcf;
      #pragma unroll
      for (int j = 0; j < 4; ++j) {
        pra[j] = bfr(ra[j]);
        prc[j] = bfr(ra[j] * cc[j]);           // product at fp32, then round
        pcf[j] = bfr(cc[j]);
      }
      dra[q * 256 + tid] = pra;
      drc[q * 256 + tid] = prc;
      dcf[q * 256 + tid] = pcf;
    }
  }
}

// MFMA split-K: grid (NKB, NM/32) = (32,8); 4 waves/block, each owns a
// 16m x 16b tile. Load-all-then-compute: all 40 dwordx4 loads issued as one
// burst into registers (launch_bounds(256,1) frees the allocator; 1 block/CU
// anyway), then 24 MFMA + bit-ops consume. One burst latency instead of 8.
// Layout (m89-verified): lane supplies row/col = lane&15 at k = 8*(lane>>4)+e;
// D: m = 4*(lane>>4)+reg, b = lane&15.
__global__ __launch_bounds__(256, 1) void k_mm(const unsigned short* __restrict__ pA,
                                               const unsigned short* __restrict__ pB,
                                               float* __restrict__ part) {
  const int tid  = threadIdx.x;
  const int kb   = blockIdx.x;          // k-block
  const int mt   = blockIdx.y;          // m-tile of 32
  const int wv   = tid >> 6;
  const int mw   = wv >> 1, bw = wv & 1;
  const int lane = tid & 63;
  const int lr   = lane & 15, lk = lane >> 4;

  const int m = mt * 32 + mw * 16 + lr;   // A-side row this lane supplies
  const int b = bw * 16 + lr;             // B-side col this lane supplies

  const unsigned short* Arow = pA + (size_t)m * NG;
  const unsigned short* Bra  = pB + 0 * (size_t)NB * NG + (size_t)b * NG;
  const unsigned short* Brc  = pB + 1 * (size_t)NB * NG + (size_t)b * NG;
  const unsigned short* Bcf  = pB + 2 * (size_t)NB * NG + (size_t)b * NG;

  // ---- load phase: 8 chunks x 4 streams, all in flight
  int4   awv[8];
  bf16x8 frav[8], frcv[8], fcfv[8];
  #pragma unroll
  for (int c = 0; c < 8; ++c) {
    const int g = kb * KR + c * 32 + lk * 8;
    awv[c]  = *reinterpret_cast<const int4*>(Arow + g);
    frav[c] = *reinterpret_cast<const bf16x8*>(Bra + g);
    frcv[c] = *reinterpret_cast<const bf16x8*>(Brc + g);
    fcfv[c] = *reinterpret_cast<const bf16x8*>(Bcf + g);
  }

  // ---- compute phase
  f32x4 accA = {0.f, 0.f, 0.f, 0.f};
  f32x4 accB = {0.f, 0.f, 0.f, 0.f};
  f32x4 accC = {0.f, 0.f, 0.f, 0.f};
  #pragma unroll
  for (int c = 0; c < 8; ++c) {
    const int4 aw = awv[c];
    int4 iaw, nfw;
    iaw.x = aw.x & 0x7FFF7FFF;  iaw.y = aw.y & 0x7FFF7FFF;
    iaw.z = aw.z & 0x7FFF7FFF;  iaw.w = aw.w & 0x7FFF7FFF;
    // sign bits -> bf16 1.0 per halfword: (t>>15)*0x3F80 (no cross-terms)
    nfw.x = (int)(((unsigned)(aw.x & 0x80008000) >> 15) * 0x3F80u);
    nfw.y = (int)(((unsigned)(aw.y & 0x80008000) >> 15) * 0x3F80u);
    nfw.z = (int)(((unsigned)(aw.z & 0x80008000) >> 15) * 0x3F80u);
    nfw.w = (int)(((unsigned)(aw.w & 0x80008000) >> 15) * 0x3F80u);
    const bf16x8 fia = __builtin_bit_cast(bf16x8, iaw);
    const bf16x8 fnf = __builtin_bit_cast(bf16x8, nfw);

    accA = __builtin_amdgcn_mfma_f32_16x16x32_bf16(fia, frav[c], accA, 0, 0, 0);
    accB = __builtin_amdgcn_mfma_f32_16x16x32_bf16(fia, frcv[c], accB, 0, 0, 0);
    accC = __builtin_amdgcn_mfma_f32_16x16x32_bf16(fnf, fcfv[c], accC, 0, 0, 0);
  }

  // store: lane, reg i -> (m = mt*32 + mw*16 + 4*lk + i, b = bw*16 + lr)
  const int md = mt * 32 + mw * 16 + 4 * lk;
  const int bd = bw * 16 + lr;
  #pragma unroll
  for (int i = 0; i < 4; ++i) {
    part[((size_t)(kb * 3 + 0) * NM + md + i) * NB + bd] = accA[i];
    part[((size_t)(kb * 3 + 1) * NM + md + i) * NB + bd] = accB[i];
    part[((size_t)(kb * 3 + 2) * NM + md + i) * NB + bd] = accC[i];
  }
}

// grid NM: block m; tid = (kg 8 x b 32); coalesced part reads, LDS tree over kg.
__global__ __launch_bounds__(256) void k_final(const float* __restrict__ part,
                                               const float* __restrict__ sumN,
                                               float* __restrict__ out) {
  __shared__ float rA[256], rB[256], rC[256];
  const int tid = threadIdx.x;
  const int m   = blockIdx.x;
  const int b   = tid & 31;
  const int kg  = tid >> 5;             // 0..7, each covers 4 kb

  float sA = 0.f, sB = 0.f, sC = 0.f;
  #pragma unroll
  for (int t = 0; t < NKB / 8; ++t) {
    const int kb = kg * (NKB / 8) + t;
    const float* p = part + ((size_t)(kb * 3) * NM + m) * NB + b;
    sA += p[0];
    sB += p[(size_t)NM * NB];
    sC += p[2 * (size_t)NM * NB];
  }
  rA[tid] = sA; rB[tid] = sB; rC[tid] = sC;
  __syncthreads();
  if (tid < 128) { rA[tid] += rA[tid + 128]; rB[tid] += rB[tid + 128]; rC[tid] += rC[tid + 128]; }
  __syncthreads();
  if (tid < 64)  { rA[tid] += rA[tid + 64];  rB[tid] += rB[tid + 64];  rC[tid] += rC[tid + 64]; }
  __syncthreads();
  if (tid < 32) {
    const float a  = rA[tid] + rA[tid + 32];
    const float bb = rB[tid] + rB[tid + 32];
    const float c  = rC[tid] + rC[tid + 32];
    const float sN = sumN[m];
    out[(size_t)tid * NM + m] = (bb / (a + 1e-10f) - c / (sN + 1e-10f)) * (1.0f / (float)NG);
  }
}

extern "C" void kernel_launch(void* const* d_in, const int* in_sizes, int n_in,
                              void* d_out, int out_size, void* d_ws, size_t ws_size,
                              hipStream_t stream) {
  const float* R = (const float*)d_in[0];
  const int*   S = (const int*)d_in[1];
  const float* W = (const float*)d_in[2];
  float* out = (float*)d_out;

  char* ws = (char*)d_ws;
  unsigned short* pA = (unsigned short*)ws;                        // 4 MB
  unsigned short* pB = pA + (size_t)NM * NG;                       // 1.5 MB
  float* part = (float*)(ws + (size_t)NM * NG * 2 + (size_t)3 * NB * NG * 2);  // 3.2 MB
  float* sumN = part + (size_t)NKB * 3 * NM * NB;

  k_prep <<<dim3(NM + NB), dim3(256), 0, stream>>>(S, W, R, pA, pB, sumN);
  k_mm   <<<dim3(NKB, NM / 32), dim3(256), 0, stream>>>(pA, pB, part);
  k_final<<<dim3(NM), dim3(256), 0, stream>>>(part, sumN, out);
}